// Round 10
// baseline (557.241 us; speedup 1.0000x reference)
//
#include <hip/hip_runtime.h>
#include <hip/hip_bf16.h>
#include <math.h>

#define T 4
#define HH 64
#define HE 16
#define HD 128
#define EPSF 1e-8f

#define TE 16                     // edges per block (edge kernel)
#define ROWS 64                   // TE*T merged rows
#define LDA 168     // k-stride bf16 elems for K=160 buf: 336B (16B-aligned rows)
#define TN 16       // nodes per block (node kernel)
#define LDAN 200    // K=192 buf: 400B

using frag8 = __attribute__((ext_vector_type(8))) short;
using f32x4 = __attribute__((ext_vector_type(4))) float;

// silu via HW rcp: avoids the IEEE div expansion. ~1ulp, invisible in bf16.
__device__ __forceinline__ float silu_f(float v) {
    return v * __builtin_amdgcn_rcpf(1.f + __expf(-v));
}

// bf16 conversion via HW v_cvt_pk_bf16_f32 (RNE) — compiler lowers these.
__device__ __forceinline__ unsigned short f2b(float f) {
    __hip_bfloat16 h = __float2bfloat16(f);
    union { __hip_bfloat16 h; unsigned short u; } v; v.h = h;
    return v.u;
}
__device__ __forceinline__ unsigned pk2(float a, float b) {
    __hip_bfloat162 h2 = __float22bfloat162_rn(make_float2(a, b));
    union { __hip_bfloat162 h; unsigned u; } v; v.h = h2;
    return v.u;
}
__device__ __forceinline__ float b2f(unsigned u16) {
    union { unsigned u; float f; } v; v.u = u16 << 16; return v.f;
}
__device__ __forceinline__ void lds_fence() {
    asm volatile("s_waitcnt lgkmcnt(0)" ::: "memory");
}

// ---------------- fused prep: weights->bf16[n][k], h->bf16[n][t][64], deg hist,
//                  m_i zeroing (folded memset: overlaps with the other prep work) ----------------
__global__ void prep_fused(const float* __restrict__ w1, const float* __restrict__ w2,
                           const float* __restrict__ cw1, const float* __restrict__ nw1,
                           const float* __restrict__ nw2, unsigned short* __restrict__ wb,
                           const float* __restrict__ h, unsigned short* __restrict__ hb,
                           const int* __restrict__ ei, int* __restrict__ deg,
                           float* __restrict__ m_i,
                           int NB_H, int NB_E, int N, int E)
{
    int b = blockIdx.x;
    if (b < 336) {
        int i = b * 256 + threadIdx.x;
        if (i < 20480) {
            int n = i / 160, k = i - n * 160;
            float v;
            if (k < 128)      v = w1[k * 128 + n];
            else if (k < 144) v = w1[(129 + (k - 128)) * 128 + n];   // ea dims
            else if (k == 144) v = w1[128 * 128 + n];                 // n2 dim
            else              v = 0.f;
            wb[i] = f2b(v);
        } else if (i < 36864) {
            int j = i - 20480; int n = j >> 7, k = j & 127;
            wb[i] = f2b(w2[k * 128 + n]);
        } else if (i < 53248) {
            int j = i - 36864; int n = j >> 7, k = j & 127;
            wb[i] = f2b(cw1[k * 128 + n]);
        } else if (i < 77824) {
            int j = i - 53248; int n = j / 192, k = j - n * 192;
            wb[i] = f2b(nw1[k * 128 + n]);
        } else if (i < 86016) {
            int j = i - 77824; int n = j >> 7, k = j & 127;
            wb[i] = f2b(nw2[k * 64 + n]);
        }
    } else if (b < 336 + NB_H) {
        int i = (b - 336) * 256 + threadIdx.x;       // i = n*64 + d
        if (i < N * 64) {
            float4 v = *(const float4*)(h + (size_t)i * 4);   // all 4 t's of dim d
            int n = i >> 6, d = i & 63;
            size_t base = (size_t)n * 256 + d;
            hb[base + 0]   = f2b(v.x);
            hb[base + 64]  = f2b(v.y);
            hb[base + 128] = f2b(v.z);
            hb[base + 192] = f2b(v.w);
        }
    } else if (b < 336 + NB_H + NB_E) {
        int e = (b - 336 - NB_H) * 256 + threadIdx.x;
        if (e < E) atomicAdd(&deg[ei[e]], 1);
    } else {
        // m_i zeroing: N*512 floats = N*128 float4
        int i = (b - 336 - NB_H - NB_E) * 256 + threadIdx.x;
        if (i < N * 128) {
            float4 z = {0.f, 0.f, 0.f, 0.f};
            ((float4*)m_i)[i] = z;
        }
    }
}

__global__ __launch_bounds__(1024)
void scan_kernel(const int* __restrict__ deg, int* __restrict__ start, int N) {
    __shared__ int part[1024];
    int tid = threadIdx.x;
    int chunk = (N + 1023) >> 10;
    int b0 = tid * chunk;
    int s = 0;
    for (int i = 0; i < chunk; ++i) { int idx = b0 + i; if (idx < N) s += deg[idx]; }
    part[tid] = s;
    __syncthreads();
    for (int off = 1; off < 1024; off <<= 1) {
        int v = (tid >= off) ? part[tid - off] : 0;
        __syncthreads();
        part[tid] += v;
        __syncthreads();
    }
    int prefix = (tid > 0) ? part[tid - 1] : 0;
    for (int i = 0; i < chunk; ++i) {
        int idx = b0 + i;
        if (idx < N) { start[idx] = prefix; prefix += deg[idx]; }
    }
    if (tid == 1023) start[N] = part[1023];
}

__global__ void scatter_kernel(const int* __restrict__ ei, const int* __restrict__ start,
                               int* __restrict__ cursor, int* __restrict__ list, int E) {
    int e = blockIdx.x * 256 + threadIdx.x;
    if (e < E) {
        int r = ei[e];
        int p = atomicAdd(&cursor[r], 1);
        list[start[r] + p] = e;
    }
}

// ---------------- edge kernel: 16 CSR-ordered edges (M=64 rows), 256 threads ----------------
// 4 waves in a 1(M)x4(N) grid; each wave computes a 64-row x 32-col tile of every
// GEMM. SINGLE LDS matrix buffer: staging (K=160) -> y1 overlay -> y2 overlay.
// ~23KB LDS -> 7 blocks/CU. m_i layout [node][col][t], thread->elements tid &
// tid+256: EACH store/atomic INSTRUCTION covers a dense consecutive range per
// wave (full-line HBM writes). Per-instruction lane stride > 4B doubles write
// traffic (R6/R8 lesson — twice confirmed).
__global__ __launch_bounds__(256, 7)
void edge_kernel(const float* __restrict__ x, const unsigned short* __restrict__ hb,
                 const int* __restrict__ ei, const float* __restrict__ ea,
                 const int* __restrict__ list,
                 const unsigned short* __restrict__ w1b,
                 const unsigned short* __restrict__ w2b,
                 const unsigned short* __restrict__ cw1b,
                 const float* __restrict__ b1, const float* __restrict__ b2,
                 const float* __restrict__ cb1, const float* __restrict__ cb2,
                 const float* __restrict__ cw2,
                 float* __restrict__ m_i,
                 float* __restrict__ agg,
                 int N, int E)
{
    __shared__ unsigned short sA[ROWS * LDA];   // staging (K=160) -> y1 -> y2
    __shared__ float sXij[TE * 12];
    __shared__ float sNorm[ROWS];
    __shared__ int   sNode[TE];
    __shared__ int   sPN[2];                    // nodes of edges e0-1 and e0+TE
    __shared__ float sCoord[ROWS];              // cross-wave coord row-dot accumulator

    const int tid  = threadIdx.x;
    const int e0   = blockIdx.x * TE;
    const int lane = tid & 63;
    const int wid  = tid >> 6;                  // 0..3
    const int eb   = wid * 4;                   // wave's first local edge

    if (tid < ROWS) sCoord[tid] = 0.f;
    if (tid == 0) {
        sPN[0] = (e0 > 0)      ? ei[list[e0 - 1]]  : -2;
        sPN[1] = (e0 + TE < E) ? ei[list[e0 + TE]] : -2;
    }

    // ======== phase A: wave-local staging of 4 edges (16 rows) ========
    int node8 = 0;
    {
        int le = lane >> 1, half = lane & 1;
        int p = e0 + eb + le;
        if (lane < 8 && p < E) {
            int eid = list[p];
            node8 = ei[half ? (E + eid) : eid];
            if (half == 0) sNode[eb + le] = node8;
        }
    }
    // x_ij: lanes 0..47 compute + store; n2 lanes receive via shfl (no LDS fence)
    float xd = 0.f;
    if (lane < 48) {
        int le = lane / 12, i = lane - le * 12;   // i = axis*4 + t
        int p = e0 + eb + le;
        if (p < E) {
            int eid = list[p];
            xd = x[ei[eid] * 12 + i] - x[ei[E + eid] * 12 + i];
        }
        sXij[(eb + le) * 12 + i] = xd;
    }
    // h copy from pre-packed bf16: 4 le x (half,t,chunk)=64 tasks -> 4 iters/lane
    {
        int half = lane >> 5, t = (lane >> 3) & 3, chunk = lane & 7;
        #pragma unroll
        for (int le = 0; le < 4; ++le) {
            int p = e0 + eb + le;
            if (p < E) {
                int nid = __shfl(node8, le * 2 + half);
                uint4 v = *((const uint4*)hb + (size_t)nid * 32 + t * 8 + chunk);
                *(uint4*)&sA[((eb + le) * 4 + t) * LDA + half * 64 + chunk * 8] = v;
            }
        }
    }
    // edge_attr: 4 le x 4 chunks = 16 tasks (lanes 0..15), k 128..143
    if (lane < 16) {
        int le = lane >> 2, eh0 = (lane & 3) * 4;
        int p = e0 + eb + le;
        if (p < E) {
            const float4* ap = (const float4*)(ea + (size_t)list[p] * 64);
            float4 av[4];
            #pragma unroll
            for (int q = 0; q < 4; ++q) av[q] = ap[eh0 + q];
            #pragma unroll
            for (int t = 0; t < 4; ++t) {
                uint2 u;
                u.x = pk2(((const float*)&av[0])[t], ((const float*)&av[1])[t]);
                u.y = pk2(((const float*)&av[2])[t], ((const float*)&av[3])[t]);
                *(uint2*)&sA[((eb + le) * 4 + t) * LDA + 128 + eh0] = u;
            }
        }
    }
    // n2 via shfl (no fence needed): lane<16 handles (le = lane>>2, t = lane&3)
    {
        int sb = (lane >> 2) * 12 + (lane & 3);       // source lane of axis-0 term
        float a0 = __shfl(xd, sb);
        float a1 = __shfl(xd, sb + 4);
        float a2 = __shfl(xd, sb + 8);
        if (lane < 16) {
            int row = wid * 16 + lane;
            float n2 = a0 * a0 + a1 * a1 + a2 * a2;
            sNorm[row] = n2;
            uint4 z = {0, 0, 0, 0};
            *(uint4*)&sA[row * LDA + 144] = z;
            *(uint4*)&sA[row * LDA + 152] = z;
            sA[row * LDA + 144] = f2b(n2);
        }
    }
    __syncthreads();   // bar1: staging visible to all waves

    const int lrow = lane & 15;
    const int quad = lane >> 4;
    const int c0 = wid * 2;             // wave's first n-tile index

    // ---- layer 1: [64 x 160] @ [160 x 128], wave tile 64x32, bias in C-init ----
    f32x4 acc[4][2];
    {
        float bv0 = b1[c0 * 16 + lrow], bv1 = b1[(c0 + 1) * 16 + lrow];
        #pragma unroll
        for (int m = 0; m < 4; ++m) {
            acc[m][0] = (f32x4){bv0, bv0, bv0, bv0};
            acc[m][1] = (f32x4){bv1, bv1, bv1, bv1};
        }
    }
    __builtin_amdgcn_s_setprio(1);
    #pragma unroll
    for (int kb = 0; kb < 5; ++kb) {
        frag8 a[4], b[2];
        #pragma unroll
        for (int m = 0; m < 4; ++m)
            a[m] = *(const frag8*)&sA[(m * 16 + lrow) * LDA + kb * 32 + quad * 8];
        #pragma unroll
        for (int n = 0; n < 2; ++n)
            b[n] = *(const frag8*)&w1b[((c0 + n) * 16 + lrow) * 160 + kb * 32 + quad * 8];
        #pragma unroll
        for (int m = 0; m < 4; ++m)
            #pragma unroll
            for (int n = 0; n < 2; ++n)
                acc[m][n] = __builtin_amdgcn_mfma_f32_16x16x32_bf16(a[m], b[n], acc[m][n], 0, 0, 0);
    }
    __builtin_amdgcn_s_setprio(0);
    __syncthreads();   // bar2: ALL waves done reading staging (sA shared across waves)

    // y1 overlays sA cols 0..127
    #pragma unroll
    for (int n = 0; n < 2; ++n) {
        int col = (c0 + n) * 16 + lrow;
        #pragma unroll
        for (int m = 0; m < 4; ++m)
            #pragma unroll
            for (int r = 0; r < 4; ++r)
                sA[(m * 16 + quad * 4 + r) * LDA + col] = f2b(silu_f(acc[m][n][r]));
    }
    __syncthreads();   // bar3: y1 visible

    // ---- layer 2: y2 = silu(y1 @ w2 + b2) ----
    {
        float bv0 = b2[c0 * 16 + lrow], bv1 = b2[(c0 + 1) * 16 + lrow];
        #pragma unroll
        for (int m = 0; m < 4; ++m) {
            acc[m][0] = (f32x4){bv0, bv0, bv0, bv0};
            acc[m][1] = (f32x4){bv1, bv1, bv1, bv1};
        }
    }
    __builtin_amdgcn_s_setprio(1);
    #pragma unroll
    for (int kb = 0; kb < 4; ++kb) {
        frag8 a[4], b[2];
        #pragma unroll
        for (int m = 0; m < 4; ++m)
            a[m] = *(const frag8*)&sA[(m * 16 + lrow) * LDA + kb * 32 + quad * 8];
        #pragma unroll
        for (int n = 0; n < 2; ++n)
            b[n] = *(const frag8*)&w2b[((c0 + n) * 16 + lrow) * 128 + kb * 32 + quad * 8];
        #pragma unroll
        for (int m = 0; m < 4; ++m)
            #pragma unroll
            for (int n = 0; n < 2; ++n)
                acc[m][n] = __builtin_amdgcn_mfma_f32_16x16x32_bf16(a[m], b[n], acc[m][n], 0, 0, 0);
    }
    __builtin_amdgcn_s_setprio(0);
    __syncthreads();   // bar4: all waves done reading y1

    // y2 overlays sA cols 0..127
    #pragma unroll
    for (int n = 0; n < 2; ++n) {
        int col = (c0 + n) * 16 + lrow;
        #pragma unroll
        for (int m = 0; m < 4; ++m)
            #pragma unroll
            for (int r = 0; r < 4; ++r)
                sA[(m * 16 + quad * 4 + r) * LDA + col] = f2b(silu_f(acc[m][n][r]));
    }
    __syncthreads();   // bar5: y2 visible

    // ---- coord layer: c1 = silu(y2 @ cw1 + cb1); row-dot with cw2 ----
    {
        float bv0 = cb1[c0 * 16 + lrow], bv1 = cb1[(c0 + 1) * 16 + lrow];
        #pragma unroll
        for (int m = 0; m < 4; ++m) {
            acc[m][0] = (f32x4){bv0, bv0, bv0, bv0};
            acc[m][1] = (f32x4){bv1, bv1, bv1, bv1};
        }
    }
    __builtin_amdgcn_s_setprio(1);
    #pragma unroll
    for (int kb = 0; kb < 4; ++kb) {
        frag8 a[4], b[2];
        #pragma unroll
        for (int m = 0; m < 4; ++m)
            a[m] = *(const frag8*)&sA[(m * 16 + lrow) * LDA + kb * 32 + quad * 8];
        #pragma unroll
        for (int n = 0; n < 2; ++n)
            b[n] = *(const frag8*)&cw1b[((c0 + n) * 16 + lrow) * 128 + kb * 32 + quad * 8];
        #pragma unroll
        for (int m = 0; m < 4; ++m)
            #pragma unroll
            for (int n = 0; n < 2; ++n)
                acc[m][n] = __builtin_amdgcn_mfma_f32_16x16x32_bf16(a[m], b[n], acc[m][n], 0, 0, 0);
    }
    __builtin_amdgcn_s_setprio(0);
    {
        // v[j] = partial row-dot for (m = j>>2, r = j&3); reduce 16 values over
        // 16 lanes with value-folding: 15 shfls, S[j] lands on lane lrow==j.
        float v[16];
        #pragma unroll
        for (int j = 0; j < 16; ++j) v[j] = 0.f;
        #pragma unroll
        for (int n = 0; n < 2; ++n) {
            int col = (c0 + n) * 16 + lrow;
            float cw2v = cw2[col];
            #pragma unroll
            for (int m = 0; m < 4; ++m)
                #pragma unroll
                for (int r = 0; r < 4; ++r)
                    v[m * 4 + r] += silu_f(acc[m][n][r]) * cw2v;
        }
        #pragma unroll
        for (int s = 8; s >= 1; s >>= 1) {
            #pragma unroll
            for (int j = 0; j < s; ++j) {
                float sel = (lrow & s) ? v[j] : v[j + s];
                float oth = __shfl_xor(sel, s);
                v[j] = ((lrow & s) ? v[j + s] : v[j]) + oth;
            }
        }
        // lane (quad,lrow) holds S for row (lrow>>2)*16 + quad*4 + (lrow&3)
        atomicAdd(&sCoord[(lrow >> 2) * 16 + quad * 4 + (lrow & 3)], v[0]);
    }

    // ---- m_i: single-pass segmented reduction over 16 CSR-contiguous edges ----
    // tid-linear elems (tid and tid+256): each store/atomic INSTRUCTION covers a
    // packed contiguous range per wave (full-line HBM efficiency). LDS reads as
    // b32 pairs (ds_read2-fusable: word c>>1 and +32), half-select by shift+mask.
    {
        const int t = tid & 3, c = tid >> 2;
        const int cw = c >> 1;
        const unsigned shl = (c & 1) ? 0u : 16u;
        const int prevN = sPN[0], nextN = sPN[1];
        float r0 = 0.f, r1 = 0.f;
        int cur = sNode[0];
        int ls = 0;
        #pragma unroll
        for (int le = 0; le < TE; ++le) {
            int nd = sNode[le];
            if (nd != cur) {
                if (cur >= 0) {
                    float* d0 = &m_i[(size_t)cur * 512 + tid];
                    if (ls == 0 && prevN == cur) { atomicAdd(d0, r0); atomicAdd(d0 + 256, r1); }
                    else                         { d0[0] = r0; d0[256] = r1; }
                }
                r0 = 0.f; r1 = 0.f; cur = nd; ls = le;
            }
            if (nd >= 0) {
                const unsigned* rp = (const unsigned*)&sA[(le * 4 + t) * LDA];
                unsigned u0 = rp[cw];
                unsigned u1 = rp[cw + 32];
                union { unsigned u; float f; } f0, f1;
                f0.u = (u0 << shl) & 0xffff0000u;
                f1.u = (u1 << shl) & 0xffff0000u;
                r0 += f0.f; r1 += f1.f;
            }
        }
        if (cur >= 0) {
            float* d0 = &m_i[(size_t)cur * 512 + tid];
            if ((ls == 0 && prevN == cur) || nextN == cur) { atomicAdd(d0, r0); atomicAdd(d0 + 256, r1); }
            else                                           { d0[0] = r0; d0[256] = r1; }
        }
    }
    __syncthreads();   // bar6: sCoord partials complete

    // ---- coord finalize + agg: both on wave 0, so lds_fence suffices between ----
    if (tid < ROWS) {
        float c = (sCoord[tid] + cb2[0]) *
                  __builtin_amdgcn_rcpf(__builtin_amdgcn_sqrtf(sNorm[tid] + EPSF) + 1.f);
        sCoord[tid] = c;
    }
    lds_fence();       // wave-0-local ordering (finalize writes -> agg reads)

    // agg: segmented reduction of c * x_ij over runs (12 threads, one per (axis,t))
    if (tid < 12) {
        int t = tid & 3;
        float run = 0.f;
        int cur = sNode[0];
        for (int le = 0; le < TE; ++le) {
            int nd = sNode[le];
            if (nd != cur) {
                if (cur >= 0) atomicAdd(&agg[(size_t)cur * 12 + tid], run);
                run = 0.f; cur = nd;
            }
            if (nd >= 0) run += sCoord[le * 4 + t] * sXij[le * 12 + tid];
        }
        if (cur >= 0) atomicAdd(&agg[(size_t)cur * 12 + tid], run);
    }
}

// ---------------- node kernel: 16 nodes (64 rows), 256 threads, K=192 -> 128 -> 64 ----------------
// 4 waves in a 1(M)x4(N) grid: nw1/nw2 fragments loaded once per block.
// Single LDS buffer. Also performs the coord update for its 16 nodes (fused,
// issued after the staging loads — staging is the bar1 critical path).
__global__ __launch_bounds__(256, 6)
void node_kernel(const unsigned short* __restrict__ hb, const float* __restrict__ m_i,
                 const unsigned short* __restrict__ nw1b,
                 const unsigned short* __restrict__ nw2b,
                 const float* __restrict__ nb1, const float* __restrict__ nb2,
                 const float* __restrict__ x, const float* __restrict__ agg,
                 const int* __restrict__ deg,
                 float* __restrict__ out_x, float* __restrict__ out_h, int N)
{
    __shared__ unsigned short sA[64 * LDAN];

    const int tid = threadIdx.x;
    const int n0  = blockIdx.x * TN;

    // h (pre-packed bf16) -> k 0..63: ln(16) x t(4) x chunk(8) = 512 tasks
    #pragma unroll
    for (int z = 0; z < 2; ++z) {
        int c = z * 256 + tid;
        int ln = c >> 5, t = (c >> 3) & 3, chunk = c & 7;
        int node = n0 + ln;
        if (node < N) {
            uint4 v = *((const uint4*)hb + (size_t)node * 32 + t * 8 + chunk);
            *(uint4*)&sA[(ln * 4 + t) * LDAN + chunk * 8] = v;
        }
    }
    // m_i ([node][col][t] fp32) -> k 64..191
    for (int c = tid; c < 512; c += 256) {
        int ln = c >> 5, hd0 = (c & 31) * 4;
        int node = n0 + ln;
        if (node < N) {
            const float4* mp = (const float4*)(m_i + (size_t)node * 512);
            float4 mv[4];
            #pragma unroll
            for (int q = 0; q < 4; ++q) mv[q] = mp[hd0 + q];
            #pragma unroll
            for (int t = 0; t < 4; ++t) {
                uint2 u;
                u.x = pk2(((const float*)&mv[0])[t], ((const float*)&mv[1])[t]);
                u.y = pk2(((const float*)&mv[2])[t], ((const float*)&mv[3])[t]);
                *(uint2*)&sA[(ln * 4 + t) * LDAN + 64 + hd0] = u;
            }
        }
    }
    // ---- fused coord update for this block's 16 nodes (agg/deg ready) ----
    if (tid < 192) {
        int g = n0 * 12 + tid;
        if (g < N * 12) {
            int n = n0 + tid / 12;
            out_x[g] = x[g] + agg[g] * __builtin_amdgcn_rcpf(fmaxf((float)deg[n], 1.f));
        }
    }
    __syncthreads();   // bar1: staging visible

    const int lane = tid & 63;
    const int wid  = tid >> 6;
    const int lrow = lane & 15;
    const int quad = lane >> 4;
    const int c0 = wid * 2;             // wave's first n-tile index (L1)

    // ---- layer 1: [64 x 192] @ [192 x 128], wave tile 64x32, bias in C-init ----
    f32x4 acc[4][2];
    {
        float bv0 = nb1[c0 * 16 + lrow], bv1 = nb1[(c0 + 1) * 16 + lrow];
        #pragma unroll
        for (int m = 0; m < 4; ++m) {
            acc[m][0] = (f32x4){bv0, bv0, bv0, bv0};
            acc[m][1] = (f32x4){bv1, bv1, bv1, bv1};
        }
    }
    __builtin_amdgcn_s_setprio(1);
    #pragma unroll
    for (int kb = 0; kb < 6; ++kb) {
        frag8 a[4], b[2];
        #pragma unroll
        for (int m = 0; m < 4; ++m)
            a[m] = *(const frag8*)&sA[(m * 16 + lrow) * LDAN + kb * 32 + quad * 8];
        #pragma unroll
        for (int n = 0; n < 2; ++n)
            b[n] = *(const frag8*)&nw1b[((c0 + n) * 16 + lrow) * 192 + kb * 32 + quad * 8];
        #pragma unroll
        for (int m = 0; m < 4; ++m)
            #pragma unroll
            for (int n = 0; n < 2; ++n)
                acc[m][n] = __builtin_amdgcn_mfma_f32_16x16x32_bf16(a[m], b[n], acc[m][n], 0, 0, 0);
    }
    __builtin_amdgcn_s_setprio(0);
    __syncthreads();   // bar2: all waves done reading staging

    // y overlays sA cols 0..127
    #pragma unroll
    for (int n = 0; n < 2; ++n) {
        int col = (c0 + n) * 16 + lrow;
        #pragma unroll
        for (int m = 0; m < 4; ++m)
            #pragma unroll
            for (int r = 0; r < 4; ++r)
                sA[(m * 16 + quad * 4 + r) * LDAN + col] = f2b(silu_f(acc[m][n][r]));
    }
    __syncthreads();   // bar3: y visible

    // ---- layer 2: [64 x 128] @ [128 x 64], wave tile 64x16 ----
    f32x4 acc2[4];
    {
        float bv = nb2[wid * 16 + lrow];
        #pragma unroll
        for (int m = 0; m < 4; ++m) acc2[m] = (f32x4){bv, bv, bv, bv};
    }
    __builtin_amdgcn_s_setprio(1);
    #pragma unroll
    for (int kb = 0; kb < 4; ++kb) {
        frag8 a[4];
        #pragma unroll
        for (int m = 0; m < 4; ++m)
            a[m] = *(const frag8*)&sA[(m * 16 + lrow) * LDAN + kb * 32 + quad * 8];
        frag8 b = *(const frag8*)&nw2b[(wid * 16 + lrow) * 128 + kb * 32 + quad * 8];
        #pragma unroll
        for (int m = 0; m < 4; ++m)
            acc2[m] = __builtin_amdgcn_mfma_f32_16x16x32_bf16(a[m], b, acc2[m], 0, 0, 0);
    }
    __builtin_amdgcn_s_setprio(0);
    // lane (quad,lrow) holds rows m*16+quad*4+r, col wid*16+lrow:
    // node ln = m*4+quad, t = r -> float4 store per m.
    #pragma unroll
    for (int m = 0; m < 4; ++m) {
        int node = n0 + m * 4 + quad;
        if (node < N) {
            float* op = out_h + (size_t)node * 256 + (wid * 16 + lrow) * 4;
            float4 ov = { acc2[m][0], acc2[m][1], acc2[m][2], acc2[m][3] };
            *(float4*)op = ov;
        }
    }
}

extern "C" void kernel_launch(void* const* d_in, const int* in_sizes, int n_in,
                              void* d_out, int out_size, void* d_ws, size_t ws_size,
                              hipStream_t stream)
{
    const float* x   = (const float*)d_in[0];
    const float* h   = (const float*)d_in[1];
    const int*   ei  = (const int*)d_in[2];
    const float* ea  = (const float*)d_in[3];
    const float* w1  = (const float*)d_in[5];
    const float* b1  = (const float*)d_in[6];
    const float* w2  = (const float*)d_in[7];
    const float* b2  = (const float*)d_in[8];
    const float* cw1 = (const float*)d_in[9];
    const float* cb1 = (const float*)d_in[10];
    const float* cw2 = (const float*)d_in[11];
    const float* cb2 = (const float*)d_in[12];
    const float* nw1 = (const float*)d_in[13];
    const float* nb1 = (const float*)d_in[14];
    const float* nw2 = (const float*)d_in[15];
    const float* nb2 = (const float*)d_in[16];

    const int N = in_sizes[0] / 12;
    const int E = in_sizes[2] / 2;

    // ---- workspace layout (bytes); total ~55 MB ----
    char* ws = (char*)d_ws;
    unsigned short* wb = (unsigned short*)ws;              // 172032 B
    size_t o = 172032;
    int*   deg    = (int*)(ws + o);    o += (size_t)N * 4;
    int*   cursor = (int*)(ws + o);    o += (size_t)N * 4;
    float* agg    = (float*)(ws + o);  o += (size_t)N * 48;
    size_t zero_end = o;
    int*   start  = (int*)(ws + o);    o += (size_t)(N + 1) * 4;
    o = (o + 1023) & ~(size_t)1023;
    int*   list   = (int*)(ws + o);    o += (size_t)E * 4;
    o = (o + 1023) & ~(size_t)1023;
    unsigned short* hb = (unsigned short*)(ws + o); o += (size_t)N * 512;   // bf16 [n][t][64]
    o = (o + 1023) & ~(size_t)1023;
    float* m_i    = (float*)(ws + o);                      // N*512 fp32 [n][col][t] = 41 MB

    const unsigned short* w1b  = wb;
    const unsigned short* w2b  = wb + 20480;
    const unsigned short* cw1b = wb + 36864;
    const unsigned short* nw1b = wb + 53248;
    const unsigned short* nw2b = wb + 77824;

    const int NB_H = (N * 64 + 255) / 256;
    const int NB_E = (E + 255) / 256;
    const int NB_M = (N * 128 + 255) / 256;     // m_i zero blocks (float4 stores)

    hipMemsetAsync(deg, 0, zero_end - 172032, stream);      // deg + cursor + agg (small)
    prep_fused<<<336 + NB_H + NB_E + NB_M, 256, 0, stream>>>(
        w1, w2, cw1, nw1, nw2, wb, h, hb, ei, deg, m_i, NB_H, NB_E, N, E);
    scan_kernel<<<1, 1024, 0, stream>>>(deg, start, N);
    scatter_kernel<<<NB_E, 256, 0, stream>>>(ei, start, cursor, list, E);

    float* out_x = (float*)d_out;
    float* out_h = out_x + (size_t)N * 12;

    edge_kernel<<<(E + TE - 1) / TE, 256, 0, stream>>>(
        x, hb, ei, ea, list, w1b, w2b, cw1b, b1, b2, cb1, cb2, cw2, m_i, agg, N, E);
    node_kernel<<<(N + TN - 1) / TN, 256, 0, stream>>>(
        hb, m_i, nw1b, nw2b, nb1, nb2, x, agg, deg, out_x, out_h, N);
}

// Round 11
// 550.493 us; speedup vs baseline: 1.0123x; 1.0123x over previous
//
#include <hip/hip_runtime.h>
#include <hip/hip_bf16.h>
#include <math.h>

#define T 4
#define HH 64
#define HE 16
#define HD 128
#define EPSF 1e-8f

#define TE 16                     // edges per block (edge kernel)
#define ROWS 64                   // TE*T merged rows
#define LDA 168     // k-stride bf16 elems for K=160 buf: 336B (16B-aligned rows)
#define TN 16       // nodes per block (node kernel)
#define LDAN 200    // K=192 buf: 400B

using frag8 = __attribute__((ext_vector_type(8))) short;
using f32x4 = __attribute__((ext_vector_type(4))) float;

// silu via HW rcp: avoids the IEEE div expansion. ~1ulp, invisible in bf16.
__device__ __forceinline__ float silu_f(float v) {
    return v * __builtin_amdgcn_rcpf(1.f + __expf(-v));
}

// bf16 conversion via HW v_cvt_pk_bf16_f32 (RNE) — compiler lowers these.
__device__ __forceinline__ unsigned short f2b(float f) {
    __hip_bfloat16 h = __float2bfloat16(f);
    union { __hip_bfloat16 h; unsigned short u; } v; v.h = h;
    return v.u;
}
__device__ __forceinline__ unsigned pk2(float a, float b) {
    __hip_bfloat162 h2 = __float22bfloat162_rn(make_float2(a, b));
    union { __hip_bfloat162 h; unsigned u; } v; v.h = h2;
    return v.u;
}
__device__ __forceinline__ float b2f(unsigned u16) {
    union { unsigned u; float f; } v; v.u = u16 << 16; return v.f;
}
__device__ __forceinline__ void lds_fence() {
    asm volatile("s_waitcnt lgkmcnt(0)" ::: "memory");
}

// ---------------- fused prep: weights->bf16[n][k], h->bf16[n][t][64], deg hist,
//                  m_i zeroing (folded memset: overlaps with the other prep work) ----------------
__global__ void prep_fused(const float* __restrict__ w1, const float* __restrict__ w2,
                           const float* __restrict__ cw1, const float* __restrict__ nw1,
                           const float* __restrict__ nw2, unsigned short* __restrict__ wb,
                           const float* __restrict__ h, unsigned short* __restrict__ hb,
                           const int* __restrict__ ei, int* __restrict__ deg,
                           float* __restrict__ m_i,
                           int NB_H, int NB_E, int N, int E)
{
    int b = blockIdx.x;
    if (b < 336) {
        int i = b * 256 + threadIdx.x;
        if (i < 20480) {
            int n = i / 160, k = i - n * 160;
            float v;
            if (k < 128)      v = w1[k * 128 + n];
            else if (k < 144) v = w1[(129 + (k - 128)) * 128 + n];   // ea dims
            else if (k == 144) v = w1[128 * 128 + n];                 // n2 dim
            else              v = 0.f;
            wb[i] = f2b(v);
        } else if (i < 36864) {
            int j = i - 20480; int n = j >> 7, k = j & 127;
            wb[i] = f2b(w2[k * 128 + n]);
        } else if (i < 53248) {
            int j = i - 36864; int n = j >> 7, k = j & 127;
            wb[i] = f2b(cw1[k * 128 + n]);
        } else if (i < 77824) {
            int j = i - 53248; int n = j / 192, k = j - n * 192;
            wb[i] = f2b(nw1[k * 128 + n]);
        } else if (i < 86016) {
            int j = i - 77824; int n = j >> 7, k = j & 127;
            wb[i] = f2b(nw2[k * 64 + n]);
        }
    } else if (b < 336 + NB_H) {
        int i = (b - 336) * 256 + threadIdx.x;       // i = n*64 + d
        if (i < N * 64) {
            float4 v = *(const float4*)(h + (size_t)i * 4);   // all 4 t's of dim d
            int n = i >> 6, d = i & 63;
            size_t base = (size_t)n * 256 + d;
            hb[base + 0]   = f2b(v.x);
            hb[base + 64]  = f2b(v.y);
            hb[base + 128] = f2b(v.z);
            hb[base + 192] = f2b(v.w);
        }
    } else if (b < 336 + NB_H + NB_E) {
        int e = (b - 336 - NB_H) * 256 + threadIdx.x;
        if (e < E) atomicAdd(&deg[ei[e]], 1);
    } else {
        // m_i zeroing: N*512 floats = N*128 float4
        int i = (b - 336 - NB_H - NB_E) * 256 + threadIdx.x;
        if (i < N * 128) {
            float4 z = {0.f, 0.f, 0.f, 0.f};
            ((float4*)m_i)[i] = z;
        }
    }
}

__global__ __launch_bounds__(1024)
void scan_kernel(const int* __restrict__ deg, int* __restrict__ start, int N) {
    __shared__ int part[1024];
    int tid = threadIdx.x;
    int chunk = (N + 1023) >> 10;
    int b0 = tid * chunk;
    int s = 0;
    for (int i = 0; i < chunk; ++i) { int idx = b0 + i; if (idx < N) s += deg[idx]; }
    part[tid] = s;
    __syncthreads();
    for (int off = 1; off < 1024; off <<= 1) {
        int v = (tid >= off) ? part[tid - off] : 0;
        __syncthreads();
        part[tid] += v;
        __syncthreads();
    }
    int prefix = (tid > 0) ? part[tid - 1] : 0;
    for (int i = 0; i < chunk; ++i) {
        int idx = b0 + i;
        if (idx < N) { start[idx] = prefix; prefix += deg[idx]; }
    }
    if (tid == 1023) start[N] = part[1023];
}

__global__ void scatter_kernel(const int* __restrict__ ei, const int* __restrict__ start,
                               int* __restrict__ cursor, int* __restrict__ list, int E) {
    int e = blockIdx.x * 256 + threadIdx.x;
    if (e < E) {
        int r = ei[e];
        int p = atomicAdd(&cursor[r], 1);
        list[start[r] + p] = e;
    }
}

// ---------------- edge kernel: 16 CSR-ordered edges (M=64 rows), 256 threads ----------------
// 4 waves in a 1(M)x4(N) grid; each wave computes a 64-row x 32-col tile of every
// GEMM. SINGLE LDS matrix buffer: staging (K=160) -> y1 overlay -> y2 overlay.
// ~23KB LDS -> 7 blocks/CU. m_i layout [node][col][t], thread->elements tid &
// tid+256: EACH store/atomic INSTRUCTION covers a dense consecutive range per
// wave (full-line HBM writes). Per-instruction lane stride > 4B doubles write
// traffic (R6/R8 lesson — twice confirmed). Phase A / m_i loop use the R9
// codegen (R10's shfl-n2 and b32-pair variants both measured slower).
__global__ __launch_bounds__(256, 7)
void edge_kernel(const float* __restrict__ x, const unsigned short* __restrict__ hb,
                 const int* __restrict__ ei, const float* __restrict__ ea,
                 const int* __restrict__ list,
                 const unsigned short* __restrict__ w1b,
                 const unsigned short* __restrict__ w2b,
                 const unsigned short* __restrict__ cw1b,
                 const float* __restrict__ b1, const float* __restrict__ b2,
                 const float* __restrict__ cb1, const float* __restrict__ cb2,
                 const float* __restrict__ cw2,
                 float* __restrict__ m_i,
                 float* __restrict__ agg,
                 int N, int E)
{
    __shared__ unsigned short sA[ROWS * LDA];   // staging (K=160) -> y1 -> y2
    __shared__ float sXij[TE * 12];
    __shared__ float sNorm[ROWS];
    __shared__ int   sNode[TE];
    __shared__ int   sPN[2];                    // nodes of edges e0-1 and e0+TE
    __shared__ float sCoord[ROWS];              // cross-wave coord row-dot accumulator

    const int tid  = threadIdx.x;
    const int e0   = blockIdx.x * TE;
    const int lane = tid & 63;
    const int wid  = tid >> 6;                  // 0..3
    const int eb   = wid * 4;                   // wave's first local edge

    if (tid < ROWS) sCoord[tid] = 0.f;
    if (tid == 0) {
        sPN[0] = (e0 > 0)      ? ei[list[e0 - 1]]  : -2;
        sPN[1] = (e0 + TE < E) ? ei[list[e0 + TE]] : -2;
    }

    // ======== phase A: wave-local staging of 4 edges (16 rows) ========
    int node8 = 0;
    {
        int le = lane >> 1, half = lane & 1;
        int p = e0 + eb + le;
        if (lane < 8 && p < E) {
            int eid = list[p];
            node8 = ei[half ? (E + eid) : eid];
            if (half == 0) sNode[eb + le] = node8;
        }
    }
    // x_ij (lanes 0..47)
    if (lane < 48) {
        int le = lane / 12, i = lane - le * 12;   // i = axis*4 + t
        int p = e0 + eb + le;
        float d = 0.f;
        if (p < E) {
            int eid = list[p];
            d = x[ei[eid] * 12 + i] - x[ei[E + eid] * 12 + i];
        }
        sXij[(eb + le) * 12 + i] = d;
    }
    // h copy from pre-packed bf16: 4 le x (half,t,chunk)=64 tasks -> 4 iters/lane
    {
        int half = lane >> 5, t = (lane >> 3) & 3, chunk = lane & 7;
        #pragma unroll
        for (int le = 0; le < 4; ++le) {
            int p = e0 + eb + le;
            if (p < E) {
                int nid = __shfl(node8, le * 2 + half);
                uint4 v = *((const uint4*)hb + (size_t)nid * 32 + t * 8 + chunk);
                *(uint4*)&sA[((eb + le) * 4 + t) * LDA + half * 64 + chunk * 8] = v;
            }
        }
    }
    // edge_attr: 4 le x 4 chunks = 16 tasks (lanes 0..15), k 128..143
    if (lane < 16) {
        int le = lane >> 2, eh0 = (lane & 3) * 4;
        int p = e0 + eb + le;
        if (p < E) {
            const float4* ap = (const float4*)(ea + (size_t)list[p] * 64);
            float4 av[4];
            #pragma unroll
            for (int q = 0; q < 4; ++q) av[q] = ap[eh0 + q];
            #pragma unroll
            for (int t = 0; t < 4; ++t) {
                uint2 u;
                u.x = pk2(((const float*)&av[0])[t], ((const float*)&av[1])[t]);
                u.y = pk2(((const float*)&av[2])[t], ((const float*)&av[3])[t]);
                *(uint2*)&sA[((eb + le) * 4 + t) * LDA + 128 + eh0] = u;
            }
        }
    }
    lds_fence();   // xij writes (lanes 0..47) -> n2 reads (lanes 0..15), same wave
    // n2 at k=144, zero-pad 145..159 (lanes 0..15 -> wave's 16 rows)
    if (lane < 16) {
        int row = wid * 16 + lane;
        int le = eb + (lane >> 2), t = lane & 3;
        float a0 = sXij[le * 12 + t], a1 = sXij[le * 12 + 4 + t], a2 = sXij[le * 12 + 8 + t];
        float n2 = a0 * a0 + a1 * a1 + a2 * a2;
        sNorm[row] = n2;
        uint4 z = {0, 0, 0, 0};
        *(uint4*)&sA[row * LDA + 144] = z;
        *(uint4*)&sA[row * LDA + 152] = z;
        sA[row * LDA + 144] = f2b(n2);
    }
    __syncthreads();   // bar1: staging visible to all waves

    const int lrow = lane & 15;
    const int quad = lane >> 4;
    const int c0 = wid * 2;             // wave's first n-tile index

    // ---- layer 1: [64 x 160] @ [160 x 128], wave tile 64x32, bias in C-init ----
    f32x4 acc[4][2];
    {
        float bv0 = b1[c0 * 16 + lrow], bv1 = b1[(c0 + 1) * 16 + lrow];
        #pragma unroll
        for (int m = 0; m < 4; ++m) {
            acc[m][0] = (f32x4){bv0, bv0, bv0, bv0};
            acc[m][1] = (f32x4){bv1, bv1, bv1, bv1};
        }
    }
    __builtin_amdgcn_s_setprio(1);
    #pragma unroll
    for (int kb = 0; kb < 5; ++kb) {
        frag8 a[4], b[2];
        #pragma unroll
        for (int m = 0; m < 4; ++m)
            a[m] = *(const frag8*)&sA[(m * 16 + lrow) * LDA + kb * 32 + quad * 8];
        #pragma unroll
        for (int n = 0; n < 2; ++n)
            b[n] = *(const frag8*)&w1b[((c0 + n) * 16 + lrow) * 160 + kb * 32 + quad * 8];
        #pragma unroll
        for (int m = 0; m < 4; ++m)
            #pragma unroll
            for (int n = 0; n < 2; ++n)
                acc[m][n] = __builtin_amdgcn_mfma_f32_16x16x32_bf16(a[m], b[n], acc[m][n], 0, 0, 0);
    }
    __builtin_amdgcn_s_setprio(0);
    __syncthreads();   // bar2: ALL waves done reading staging (sA shared across waves)

    // y1 overlays sA cols 0..127
    #pragma unroll
    for (int n = 0; n < 2; ++n) {
        int col = (c0 + n) * 16 + lrow;
        #pragma unroll
        for (int m = 0; m < 4; ++m)
            #pragma unroll
            for (int r = 0; r < 4; ++r)
                sA[(m * 16 + quad * 4 + r) * LDA + col] = f2b(silu_f(acc[m][n][r]));
    }
    __syncthreads();   // bar3: y1 visible

    // ---- layer 2: y2 = silu(y1 @ w2 + b2) ----
    {
        float bv0 = b2[c0 * 16 + lrow], bv1 = b2[(c0 + 1) * 16 + lrow];
        #pragma unroll
        for (int m = 0; m < 4; ++m) {
            acc[m][0] = (f32x4){bv0, bv0, bv0, bv0};
            acc[m][1] = (f32x4){bv1, bv1, bv1, bv1};
        }
    }
    __builtin_amdgcn_s_setprio(1);
    #pragma unroll
    for (int kb = 0; kb < 4; ++kb) {
        frag8 a[4], b[2];
        #pragma unroll
        for (int m = 0; m < 4; ++m)
            a[m] = *(const frag8*)&sA[(m * 16 + lrow) * LDA + kb * 32 + quad * 8];
        #pragma unroll
        for (int n = 0; n < 2; ++n)
            b[n] = *(const frag8*)&w2b[((c0 + n) * 16 + lrow) * 128 + kb * 32 + quad * 8];
        #pragma unroll
        for (int m = 0; m < 4; ++m)
            #pragma unroll
            for (int n = 0; n < 2; ++n)
                acc[m][n] = __builtin_amdgcn_mfma_f32_16x16x32_bf16(a[m], b[n], acc[m][n], 0, 0, 0);
    }
    __builtin_amdgcn_s_setprio(0);
    __syncthreads();   // bar4: all waves done reading y1

    // y2 overlays sA cols 0..127
    #pragma unroll
    for (int n = 0; n < 2; ++n) {
        int col = (c0 + n) * 16 + lrow;
        #pragma unroll
        for (int m = 0; m < 4; ++m)
            #pragma unroll
            for (int r = 0; r < 4; ++r)
                sA[(m * 16 + quad * 4 + r) * LDA + col] = f2b(silu_f(acc[m][n][r]));
    }
    __syncthreads();   // bar5: y2 visible

    // ---- coord layer: c1 = silu(y2 @ cw1 + cb1); row-dot with cw2 ----
    {
        float bv0 = cb1[c0 * 16 + lrow], bv1 = cb1[(c0 + 1) * 16 + lrow];
        #pragma unroll
        for (int m = 0; m < 4; ++m) {
            acc[m][0] = (f32x4){bv0, bv0, bv0, bv0};
            acc[m][1] = (f32x4){bv1, bv1, bv1, bv1};
        }
    }
    __builtin_amdgcn_s_setprio(1);
    #pragma unroll
    for (int kb = 0; kb < 4; ++kb) {
        frag8 a[4], b[2];
        #pragma unroll
        for (int m = 0; m < 4; ++m)
            a[m] = *(const frag8*)&sA[(m * 16 + lrow) * LDA + kb * 32 + quad * 8];
        #pragma unroll
        for (int n = 0; n < 2; ++n)
            b[n] = *(const frag8*)&cw1b[((c0 + n) * 16 + lrow) * 128 + kb * 32 + quad * 8];
        #pragma unroll
        for (int m = 0; m < 4; ++m)
            #pragma unroll
            for (int n = 0; n < 2; ++n)
                acc[m][n] = __builtin_amdgcn_mfma_f32_16x16x32_bf16(a[m], b[n], acc[m][n], 0, 0, 0);
    }
    __builtin_amdgcn_s_setprio(0);
    {
        // v[j] = partial row-dot for (m = j>>2, r = j&3); reduce 16 values over
        // 16 lanes with value-folding: 15 shfls, S[j] lands on lane lrow==j.
        float v[16];
        #pragma unroll
        for (int j = 0; j < 16; ++j) v[j] = 0.f;
        #pragma unroll
        for (int n = 0; n < 2; ++n) {
            int col = (c0 + n) * 16 + lrow;
            float cw2v = cw2[col];
            #pragma unroll
            for (int m = 0; m < 4; ++m)
                #pragma unroll
                for (int r = 0; r < 4; ++r)
                    v[m * 4 + r] += silu_f(acc[m][n][r]) * cw2v;
        }
        #pragma unroll
        for (int s = 8; s >= 1; s >>= 1) {
            #pragma unroll
            for (int j = 0; j < s; ++j) {
                float sel = (lrow & s) ? v[j] : v[j + s];
                float oth = __shfl_xor(sel, s);
                v[j] = ((lrow & s) ? v[j + s] : v[j]) + oth;
            }
        }
        // lane (quad,lrow) holds S for row (lrow>>2)*16 + quad*4 + (lrow&3)
        atomicAdd(&sCoord[(lrow >> 2) * 16 + quad * 4 + (lrow & 3)], v[0]);
    }

    // ---- m_i: single-pass segmented reduction over 16 CSR-contiguous edges ----
    // tid-linear elems (tid and tid+256): each store/atomic INSTRUCTION covers a
    // packed contiguous range per wave (full-line HBM efficiency). Plain stores
    // for block-interior runs, atomics only for boundary-straddling runs.
    {
        const int t = tid & 3, c = tid >> 2;
        const int prevN = sPN[0], nextN = sPN[1];
        float r0 = 0.f, r1 = 0.f;
        int cur = sNode[0];
        int ls = 0;
        #pragma unroll
        for (int le = 0; le < TE; ++le) {
            int nd = sNode[le];
            if (nd != cur) {
                if (cur >= 0) {
                    float* d0 = &m_i[(size_t)cur * 512 + tid];
                    if (ls == 0 && prevN == cur) { atomicAdd(d0, r0); atomicAdd(d0 + 256, r1); }
                    else                         { d0[0] = r0; d0[256] = r1; }
                }
                r0 = 0.f; r1 = 0.f; cur = nd; ls = le;
            }
            if (nd >= 0) {
                r0 += b2f((unsigned)sA[(le * 4 + t) * LDA + c]);
                r1 += b2f((unsigned)sA[(le * 4 + t) * LDA + c + 64]);
            }
        }
        if (cur >= 0) {
            float* d0 = &m_i[(size_t)cur * 512 + tid];
            if ((ls == 0 && prevN == cur) || nextN == cur) { atomicAdd(d0, r0); atomicAdd(d0 + 256, r1); }
            else                                           { d0[0] = r0; d0[256] = r1; }
        }
    }
    __syncthreads();   // bar6: sCoord partials complete

    // ---- coord finalize + agg: both on wave 0, so lds_fence suffices between ----
    if (tid < ROWS) {
        float c = (sCoord[tid] + cb2[0]) *
                  __builtin_amdgcn_rcpf(__builtin_amdgcn_sqrtf(sNorm[tid] + EPSF) + 1.f);
        sCoord[tid] = c;
    }
    lds_fence();       // wave-0-local ordering (finalize writes -> agg reads)

    // agg: segmented reduction of c * x_ij over runs (12 threads, one per (axis,t))
    if (tid < 12) {
        int t = tid & 3;
        float run = 0.f;
        int cur = sNode[0];
        for (int le = 0; le < TE; ++le) {
            int nd = sNode[le];
            if (nd != cur) {
                if (cur >= 0) atomicAdd(&agg[(size_t)cur * 12 + tid], run);
                run = 0.f; cur = nd;
            }
            if (nd >= 0) run += sCoord[le * 4 + t] * sXij[le * 12 + tid];
        }
        if (cur >= 0) atomicAdd(&agg[(size_t)cur * 12 + tid], run);
    }
}

// ---------------- node kernel: 16 nodes (64 rows), 256 threads, K=192 -> 128 -> 64 ----------------
// 4 waves in a 1(M)x4(N) grid: nw1/nw2 fragments loaded once per block.
// Single LDS buffer. Also performs the coord update for its 16 nodes (fused,
// issued after the staging loads — staging is the bar1 critical path).
__global__ __launch_bounds__(256, 6)
void node_kernel(const unsigned short* __restrict__ hb, const float* __restrict__ m_i,
                 const unsigned short* __restrict__ nw1b,
                 const unsigned short* __restrict__ nw2b,
                 const float* __restrict__ nb1, const float* __restrict__ nb2,
                 const float* __restrict__ x, const float* __restrict__ agg,
                 const int* __restrict__ deg,
                 float* __restrict__ out_x, float* __restrict__ out_h, int N)
{
    __shared__ unsigned short sA[64 * LDAN];

    const int tid = threadIdx.x;
    const int n0  = blockIdx.x * TN;

    // h (pre-packed bf16) -> k 0..63: ln(16) x t(4) x chunk(8) = 512 tasks
    #pragma unroll
    for (int z = 0; z < 2; ++z) {
        int c = z * 256 + tid;
        int ln = c >> 5, t = (c >> 3) & 3, chunk = c & 7;
        int node = n0 + ln;
        if (node < N) {
            uint4 v = *((const uint4*)hb + (size_t)node * 32 + t * 8 + chunk);
            *(uint4*)&sA[(ln * 4 + t) * LDAN + chunk * 8] = v;
        }
    }
    // m_i ([node][col][t] fp32) -> k 64..191
    for (int c = tid; c < 512; c += 256) {
        int ln = c >> 5, hd0 = (c & 31) * 4;
        int node = n0 + ln;
        if (node < N) {
            const float4* mp = (const float4*)(m_i + (size_t)node * 512);
            float4 mv[4];
            #pragma unroll
            for (int q = 0; q < 4; ++q) mv[q] = mp[hd0 + q];
            #pragma unroll
            for (int t = 0; t < 4; ++t) {
                uint2 u;
                u.x = pk2(((const float*)&mv[0])[t], ((const float*)&mv[1])[t]);
                u.y = pk2(((const float*)&mv[2])[t], ((const float*)&mv[3])[t]);
                *(uint2*)&sA[(ln * 4 + t) * LDAN + 64 + hd0] = u;
            }
        }
    }
    // ---- fused coord update for this block's 16 nodes (agg/deg ready) ----
    if (tid < 192) {
        int g = n0 * 12 + tid;
        if (g < N * 12) {
            int n = n0 + tid / 12;
            out_x[g] = x[g] + agg[g] * __builtin_amdgcn_rcpf(fmaxf((float)deg[n], 1.f));
        }
    }
    __syncthreads();   // bar1: staging visible

    const int lane = tid & 63;
    const int wid  = tid >> 6;
    const int lrow = lane & 15;
    const int quad = lane >> 4;
    const int c0 = wid * 2;             // wave's first n-tile index (L1)

    // ---- layer 1: [64 x 192] @ [192 x 128], wave tile 64x32, bias in C-init ----
    f32x4 acc[4][2];
    {
        float bv0 = nb1[c0 * 16 + lrow], bv1 = nb1[(c0 + 1) * 16 + lrow];
        #pragma unroll
        for (int m = 0; m < 4; ++m) {
            acc[m][0] = (f32x4){bv0, bv0, bv0, bv0};
            acc[m][1] = (f32x4){bv1, bv1, bv1, bv1};
        }
    }
    __builtin_amdgcn_s_setprio(1);
    #pragma unroll
    for (int kb = 0; kb < 6; ++kb) {
        frag8 a[4], b[2];
        #pragma unroll
        for (int m = 0; m < 4; ++m)
            a[m] = *(const frag8*)&sA[(m * 16 + lrow) * LDAN + kb * 32 + quad * 8];
        #pragma unroll
        for (int n = 0; n < 2; ++n)
            b[n] = *(const frag8*)&nw1b[((c0 + n) * 16 + lrow) * 192 + kb * 32 + quad * 8];
        #pragma unroll
        for (int m = 0; m < 4; ++m)
            #pragma unroll
            for (int n = 0; n < 2; ++n)
                acc[m][n] = __builtin_amdgcn_mfma_f32_16x16x32_bf16(a[m], b[n], acc[m][n], 0, 0, 0);
    }
    __builtin_amdgcn_s_setprio(0);
    __syncthreads();   // bar2: all waves done reading staging

    // y overlays sA cols 0..127
    #pragma unroll
    for (int n = 0; n < 2; ++n) {
        int col = (c0 + n) * 16 + lrow;
        #pragma unroll
        for (int m = 0; m < 4; ++m)
            #pragma unroll
            for (int r = 0; r < 4; ++r)
                sA[(m * 16 + quad * 4 + r) * LDAN + col] = f2b(silu_f(acc[m][n][r]));
    }
    __syncthreads();   // bar3: y visible

    // ---- layer 2: [64 x 128] @ [128 x 64], wave tile 64x16 ----
    f32x4 acc2[4];
    {
        float bv = nb2[wid * 16 + lrow];
        #pragma unroll
        for (int m = 0; m < 4; ++m) acc2[m] = (f32x4){bv, bv, bv, bv};
    }
    __builtin_amdgcn_s_setprio(1);
    #pragma unroll
    for (int kb = 0; kb < 4; ++kb) {
        frag8 a[4];
        #pragma unroll
        for (int m = 0; m < 4; ++m)
            a[m] = *(const frag8*)&sA[(m * 16 + lrow) * LDAN + kb * 32 + quad * 8];
        frag8 b = *(const frag8*)&nw2b[(wid * 16 + lrow) * 128 + kb * 32 + quad * 8];
        #pragma unroll
        for (int m = 0; m < 4; ++m)
            acc2[m] = __builtin_amdgcn_mfma_f32_16x16x32_bf16(a[m], b, acc2[m], 0, 0, 0);
    }
    __builtin_amdgcn_s_setprio(0);
    // lane (quad,lrow) holds rows m*16+quad*4+r, col wid*16+lrow:
    // node ln = m*4+quad, t = r -> float4 store per m.
    #pragma unroll
    for (int m = 0; m < 4; ++m) {
        int node = n0 + m * 4 + quad;
        if (node < N) {
            float* op = out_h + (size_t)node * 256 + (wid * 16 + lrow) * 4;
            float4 ov = { acc2[m][0], acc2[m][1], acc2[m][2], acc2[m][3] };
            *(float4*)op = ov;
        }
    }
}

extern "C" void kernel_launch(void* const* d_in, const int* in_sizes, int n_in,
                              void* d_out, int out_size, void* d_ws, size_t ws_size,
                              hipStream_t stream)
{
    const float* x   = (const float*)d_in[0];
    const float* h   = (const float*)d_in[1];
    const int*   ei  = (const int*)d_in[2];
    const float* ea  = (const float*)d_in[3];
    const float* w1  = (const float*)d_in[5];
    const float* b1  = (const float*)d_in[6];
    const float* w2  = (const float*)d_in[7];
    const float* b2  = (const float*)d_in[8];
    const float* cw1 = (const float*)d_in[9];
    const float* cb1 = (const float*)d_in[10];
    const float* cw2 = (const float*)d_in[11];
    const float* cb2 = (const float*)d_in[12];
    const float* nw1 = (const float*)d_in[13];
    const float* nb1 = (const float*)d_in[14];
    const float* nw2 = (const float*)d_in[15];
    const float* nb2 = (const float*)d_in[16];

    const int N = in_sizes[0] / 12;
    const int E = in_sizes[2] / 2;

    // ---- workspace layout (bytes); total ~55 MB ----
    char* ws = (char*)d_ws;
    unsigned short* wb = (unsigned short*)ws;              // 172032 B
    size_t o = 172032;
    int*   deg    = (int*)(ws + o);    o += (size_t)N * 4;
    int*   cursor = (int*)(ws + o);    o += (size_t)N * 4;
    float* agg    = (float*)(ws + o);  o += (size_t)N * 48;
    size_t zero_end = o;
    int*   start  = (int*)(ws + o);    o += (size_t)(N + 1) * 4;
    o = (o + 1023) & ~(size_t)1023;
    int*   list   = (int*)(ws + o);    o += (size_t)E * 4;
    o = (o + 1023) & ~(size_t)1023;
    unsigned short* hb = (unsigned short*)(ws + o); o += (size_t)N * 512;   // bf16 [n][t][64]
    o = (o + 1023) & ~(size_t)1023;
    float* m_i    = (float*)(ws + o);                      // N*512 fp32 [n][col][t] = 41 MB

    const unsigned short* w1b  = wb;
    const unsigned short* w2b  = wb + 20480;
    const unsigned short* cw1b = wb + 36864;
    const unsigned short* nw1b = wb + 53248;
    const unsigned short* nw2b = wb + 77824;

    const int NB_H = (N * 64 + 255) / 256;
    const int NB_E = (E + 255) / 256;
    const int NB_M = (N * 128 + 255) / 256;     // m_i zero blocks (float4 stores)

    hipMemsetAsync(deg, 0, zero_end - 172032, stream);      // deg + cursor + agg (small)
    prep_fused<<<336 + NB_H + NB_E + NB_M, 256, 0, stream>>>(
        w1, w2, cw1, nw1, nw2, wb, h, hb, ei, deg, m_i, NB_H, NB_E, N, E);
    scan_kernel<<<1, 1024, 0, stream>>>(deg, start, N);
    scatter_kernel<<<NB_E, 256, 0, stream>>>(ei, start, cursor, list, E);

    float* out_x = (float*)d_out;
    float* out_h = out_x + (size_t)N * 12;

    edge_kernel<<<(E + TE - 1) / TE, 256, 0, stream>>>(
        x, hb, ei, ea, list, w1b, w2b, cw1b, b1, b2, cb1, cb2, cw2, m_i, agg, N, E);
    node_kernel<<<(N + TN - 1) / TN, 256, 0, stream>>>(
        hb, m_i, nw1b, nw2b, nb1, nb2, x, agg, deg, out_x, out_h, N);
}